// Round 4
// baseline (88.802 us; speedup 1.0000x reference)
//
#include <hip/hip_runtime.h>
#include <math.h>

#define FD 76
#define FFD 5776
#define BD 16
#define CD 256
#define KD 50
#define AD 3

typedef float f32x2 __attribute__((ext_vector_type(2)));
typedef float f32x4 __attribute__((ext_vector_type(4)));

constexpr int NCELL = BD * FFD;          // 92416
constexpr int CBLK  = 128;               // cells per block
constexpr int NBLK  = NCELL / CBLK;      // 722

// ws layout: [0..4] float accs (lxy,lwh,lobj,lcls,l2), [5] int done counter.
// memset 64 B each launch.

__device__ __forceinline__ float sigm(float x){ return 1.f/(1.f + expf(-x)); }
__device__ __forceinline__ float clg(float x){ return logf(fmaxf(x, 1e-12f)); }
__device__ __forceinline__ float bce(float o, float t){ return -(t*clg(o) + (1.f-t)*clg(1.f-o)); }

// record layout [16]: 0:tx0 1:tx1 2:ty0 3:ty1 4:c7(0.7*ta|1e30) 5:code 6:txf 7:tyf
//                     8:twl 9:thl 10:scale 11:cls 12..15 pad
__device__ __forceinline__ void make_record(const float* __restrict__ labels,
                                            int b, int k, float* __restrict__ r){
  const float AWH[9][2] = {{1.25f,1.625f},{2.f,3.75f},{4.125f,2.875f},
                           {3.75f,7.625f},{7.75f,5.625f},{7.375f,14.875f},
                           {14.5f,11.25f},{19.5f,24.75f},{46.625f,40.75f}};
  const float* l = labels + (b*KD + k)*5;
  const float cls = l[0], x = l[1], y = l[2], w = l[3], h = l[4];
  const bool valid = (cls + x + y + w + h) > 0.f;
  const float tx = x*FD, ty = y*FD, tw = w*FD, th = h*FD;
  const float ta = tw*th;
  float bestv = -1.f; int best = 0;
  #pragma unroll
  for (int n = 0; n < 9; ++n){
    const float mw = fminf(tw, AWH[n][0]), mh = fminf(th, AWH[n][1]);
    const float inter = (mw > 0.f && mh > 0.f) ? mw*mh : 0.f;
    const float iou = inter / (ta + AWH[n][0]*AWH[n][1] - inter);
    if (iou > bestv){ bestv = iou; best = n; }
  }
  const int bn = best % 3;
  const bool match = valid && (best < 3);
  const int ii = (int)tx, jj = (int)ty;
  const bool inb = (ii >= 0 && ii < FD && jj >= 0 && jj < FD);
  const float code = (match && inb) ? (float)(bn*FFD + jj*FD + ii) : -1.f;
  const float aw0 = (bn==0)?1.25f:((bn==1)?2.f:4.125f);
  const float aw1 = (bn==0)?1.625f:((bn==1)?3.75f:2.875f);
  r[0] = tx - tw*0.5f; r[1] = tx + tw*0.5f; r[2] = ty - th*0.5f; r[3] = ty + th*0.5f;
  r[4] = valid ? 0.7f*ta : 1e30f; r[5] = code;
  r[6] = tx - floorf(tx); r[7] = ty - floorf(ty);
  r[8] = logf(tw/aw0 + 1e-16f); r[9] = logf(th/aw1 + 1e-16f);
  r[10] = sqrtf(2.f - ta/(float)(FD*FD)); r[11] = cls;
}

// ---------------- mega-kernel: records + conv + epilogue + cls + finalize -------------
// 722 blocks x 256 threads. Block = 128 cells (2/lane); wave wv owns 64 channels.
__global__ __launch_bounds__(256) void fused_kernel(const float* __restrict__ xin,
    const float* __restrict__ labels, const float* __restrict__ cw,
    const float* __restrict__ cb, float* __restrict__ ws, float* __restrict__ out){
  __shared__ __align__(16) float trecL[1600];  // 2 batches x 50 records x 16
  __shared__ __align__(16) float phase[7680];  // wT[256][16] / comb[4][15][128] / xs[256]
  __shared__ float redc[20];
  __shared__ int   mitems[104];
  __shared__ int   mcnt, amlast;

  const int tid  = threadIdx.x;
  const int wv   = tid >> 6;
  const int lane = tid & 63;
  const int cell0blk = blockIdx.x*CBLK;
  const int bB0 = cell0blk / FFD;
  const int bB1 = (cell0blk + CBLK - 1) / FFD;

  if (tid == 0) mcnt = 0;
  // per-block label records (≤2 batches)
  if (tid < KD)                 make_record(labels, bB0, tid,      &trecL[tid*16]);
  else if (tid >= 64 && tid < 64 + KD && bB1 != bB0)
                                make_record(labels, bB1, tid - 64, &trecL[800 + (tid-64)*16]);
  // stage 15 W rows: wT[c*16+j] = cw[o(j)*256+c]
  #pragma unroll
  for (int j = 0; j < 15; ++j){
    const int o = (j/5)*85 + (j%5);
    phase[tid*16 + j] = cw[o*CD + tid];
  }
  phase[tid*16 + 15] = 0.f;
  __syncthreads();

  // ---- conv: lane owns cells (cell0blk + 2*lane, +1); wave owns 64 channels ----
  const int cellP = cell0blk + 2*lane;
  const int bC  = cellP / FFD;
  const int hwC = cellP - bC*FFD;
  const float* xp = xin + ((size_t)bC*CD + wv*64)*FFD + hwC;

  f32x2 acc[15];
  #pragma unroll
  for (int j = 0; j < 15; ++j) acc[j] = (f32x2){0.f, 0.f};

  f32x2 xr[16], xn[16];
  #pragma unroll
  for (int i = 0; i < 16; ++i) xr[i] = *(const f32x2*)(xp + (size_t)i*FFD);
  #pragma unroll
  for (int cc = 0; cc < 4; ++cc){
    if (cc < 3){
      #pragma unroll
      for (int i = 0; i < 16; ++i)
        xn[i] = *(const f32x2*)(xp + (size_t)((cc+1)*16 + i)*FFD);
    }
    #pragma unroll
    for (int i = 0; i < 16; ++i){
      const int c = wv*64 + cc*16 + i;
      const f32x4* wr = (const f32x4*)&phase[c*16];
      const f32x4 w0 = wr[0], w1 = wr[1], w2 = wr[2], w3 = wr[3];
      const f32x2 xv = xr[i];
      acc[0]  += w0.x*xv; acc[1]  += w0.y*xv; acc[2]  += w0.z*xv; acc[3]  += w0.w*xv;
      acc[4]  += w1.x*xv; acc[5]  += w1.y*xv; acc[6]  += w1.z*xv; acc[7]  += w1.w*xv;
      acc[8]  += w2.x*xv; acc[9]  += w2.y*xv; acc[10] += w2.z*xv; acc[11] += w2.w*xv;
      acc[12] += w3.x*xv; acc[13] += w3.y*xv; acc[14] += w3.z*xv;
    }
    if (cc < 3){
      #pragma unroll
      for (int i = 0; i < 16; ++i) xr[i] = xn[i];
    }
  }

  __syncthreads();                         // done reading wT
  #pragma unroll
  for (int j = 0; j < 15; ++j)             // comb[wv][j][cell], j-major stride 128
    *(f32x2*)&phase[wv*1920 + j*128 + 2*lane] = acc[j];
  __syncthreads();

  // ---- epilogue: 384 (cell,anchor) items; threads 0..191 take pair (2t,2t+1) ----
  float lxy = 0.f, lwh = 0.f, lobj = 0.f, lcls = 0.f, l2p = 0.f;
  if (tid < 192){
    const int it0 = 2*tid;
    const int a = it0 >> 7;
    const int cell0 = it0 & 127, cell1 = cell0 + 1;
    const float mw0 = (a==0)?1.25f:((a==1)?2.f:4.125f);
    const float mw1 = (a==0)?1.625f:((a==1)?3.75f:2.875f);
    float v0[5], v1[5];
    #pragma unroll
    for (int jj = 0; jj < 5; ++jj){
      const float bias = cb[a*85 + jj];
      float s0 = bias, s1 = bias;
      #pragma unroll
      for (int w2 = 0; w2 < 4; ++w2){
        const f32x2 q = *(const f32x2*)&phase[w2*1920 + (a*5+jj)*128 + cell0];
        s0 += q.x; s1 += q.y;
      }
      v0[jj] = s0; v1[jj] = s1;
    }
    const int g0 = cell0blk + cell0;
    const int bb = g0 / FFD;
    const int hw0 = g0 - bb*FFD,  hw1 = hw0 + 1;
    const int hh0 = hw0 / FD, wc0 = hw0 - hh0*FD;
    const int hh1 = hw1 / FD, wc1 = hw1 - hh1*FD;

    const float sx0 = sigm(v0[0]), sy0 = sigm(v0[1]), so0 = sigm(v0[4]);
    const float sx1 = sigm(v1[0]), sy1 = sigm(v1[1]), so1 = sigm(v1[4]);
    const float pw0 = expf(v0[2])*mw0, ph0 = expf(v0[3])*mw1;
    const float pw1 = expf(v1[2])*mw0, ph1 = expf(v1[3])*mw1;
    const float px0a = sx0 + wc0 - pw0*0.5f, px0b = sx0 + wc0 + pw0*0.5f;
    const float py0a = sy0 + hh0 - ph0*0.5f, py0b = sy0 + hh0 + ph0*0.5f;
    const float px1a = sx1 + wc1 - pw1*0.5f, px1b = sx1 + wc1 + pw1*0.5f;
    const float py1a = sy1 + hh1 - ph1*0.5f, py1b = sy1 + hh1 + ph1*0.5f;
    const float s7_0 = 0.7f*pw0*ph0, s7_1 = 0.7f*pw1*ph1;
    const float code0 = (float)(a*FFD + hw0), code1 = (float)(a*FFD + hw1);

    const int ub = (bb != bB0);
    const float* rb = trecL + ub*800;
    float mx0 = -1e30f, mx1 = -1e30f;
    int ks0 = -1, ks1 = -1;
    for (int k = 0; k < KD; ++k){
      const f32x4 rA = *(const f32x4*)&rb[k*16];      // tx0 tx1 ty0 ty1
      const f32x2 rB = *(const f32x2*)&rb[k*16 + 4];  // c7, code
      {
        const float dx = fminf(px0b, rA.y) - fmaxf(px0a, rA.x);
        const float dy = fminf(py0b, rA.w) - fmaxf(py0a, rA.z);
        const float inter = fmaxf(dx, 0.f)*fmaxf(dy, 0.f);
        mx0 = fmaxf(mx0, 1.7f*inter - rB.x);
        ks0 = (rB.y == code0) ? k : ks0;
      }
      {
        const float dx = fminf(px1b, rA.y) - fmaxf(px1a, rA.x);
        const float dy = fminf(py1b, rA.w) - fmaxf(py1a, rA.z);
        const float inter = fmaxf(dx, 0.f)*fmaxf(dy, 0.f);
        mx1 = fmaxf(mx1, 1.7f*inter - rB.x);
        ks1 = (rB.y == code1) ? k : ks1;
      }
    }
    if (ks0 >= 0){
      const float txf = rb[ks0*16+6], tyf = rb[ks0*16+7];
      const float twl = rb[ks0*16+8], thl = rb[ks0*16+9];
      const float sc = rb[ks0*16+10], sc2 = sc*sc;
      lxy += sc2*(bce(sx0, txf) + bce(sy0, tyf));
      l2p += (sx0-txf)*(sx0-txf) + (sy0-tyf)*(sy0-tyf);
      const float d0 = v0[2]-twl, d1 = v0[3]-thl;
      lwh += 0.5f*sc2*(d0*d0 + d1*d1);
      l2p += sc2*(d0*d0 + d1*d1);
      lobj += -clg(so0); l2p += (so0-1.f)*(so0-1.f);
      const int pos = atomicAdd(&mcnt, 1);
      if (pos < 100) mitems[pos] = cell0 | (a<<8) | (ks0<<10) | (ub<<16);
    } else if (!(mx0 > s7_0)){ lobj += -clg(1.f - so0); l2p += so0*so0; }
    if (ks1 >= 0){
      const float txf = rb[ks1*16+6], tyf = rb[ks1*16+7];
      const float twl = rb[ks1*16+8], thl = rb[ks1*16+9];
      const float sc = rb[ks1*16+10], sc2 = sc*sc;
      lxy += sc2*(bce(sx1, txf) + bce(sy1, tyf));
      l2p += (sx1-txf)*(sx1-txf) + (sy1-tyf)*(sy1-tyf);
      const float d0 = v1[2]-twl, d1 = v1[3]-thl;
      lwh += 0.5f*sc2*(d0*d0 + d1*d1);
      l2p += sc2*(d0*d0 + d1*d1);
      lobj += -clg(so1); l2p += (so1-1.f)*(so1-1.f);
      const int pos = atomicAdd(&mcnt, 1);
      if (pos < 100) mitems[pos] = cell1 | (a<<8) | (ks1<<10) | (ub<<16);
    } else if (!(mx1 > s7_1)){ lobj += -clg(1.f - so1); l2p += so1*so1; }
  }

  // ---- cls phase: matched items only (avg ~1 per block), column is L2-warm ----
  __syncthreads();                         // comb reads done; mitems/mcnt visible
  const int M = (mcnt < 100) ? mcnt : 100;
  for (int m = 0; m < M; ++m){
    const int it = mitems[m];
    const int cellE = it & 255, a = (it>>8)&3, ks = (it>>10)&63, ub = (it>>16)&1;
    const int g = cell0blk + cellE;
    const int bb = g / FFD;
    const int hw = g - bb*FFD;
    phase[tid] = xin[((size_t)bb*CD + tid)*FFD + hw];
    __syncthreads();
    if (tid < 80){
      const int o = a*85 + 5 + tid;
      const float* wr = cw + o*CD;
      float s = cb[o];
      #pragma unroll 8
      for (int c = 0; c < CD; ++c) s += phase[c]*wr[c];
      const float e = sigm(s);
      const float t = (tid == (int)trecL[ub*800 + ks*16 + 11]) ? 1.f : 0.f;
      lcls += bce(e, t);
      l2p  += (e - t)*(e - t);
    }
    __syncthreads();
  }

  // ---- reduce 5 components: wave shuffle -> LDS -> 5 atomicAdds ----
  #pragma unroll
  for (int o = 32; o > 0; o >>= 1){
    lxy  += __shfl_down(lxy,  o, 64);
    lwh  += __shfl_down(lwh,  o, 64);
    lobj += __shfl_down(lobj, o, 64);
    lcls += __shfl_down(lcls, o, 64);
    l2p  += __shfl_down(l2p,  o, 64);
  }
  if (lane == 0){
    redc[wv*5+0] = lxy; redc[wv*5+1] = lwh; redc[wv*5+2] = lobj;
    redc[wv*5+3] = lcls; redc[wv*5+4] = l2p;
  }
  __syncthreads();
  if (tid < 5)
    atomicAdd(ws + tid, redc[tid] + redc[5+tid] + redc[10+tid] + redc[15+tid]);
  __syncthreads();                         // drains tid<5's atomic (vmcnt0 at barrier)
  __threadfence();
  if (tid == 0){
    const int old = atomicAdd((int*)ws + 5, 1);
    amlast = (old == NBLK - 1);
  }
  __syncthreads();
  if (amlast && tid == 0){
    __threadfence();
    const float a0 = atomicAdd(ws+0, 0.f), a1 = atomicAdd(ws+1, 0.f);
    const float a2 = atomicAdd(ws+2, 0.f), a3 = atomicAdd(ws+3, 0.f);
    const float a4 = atomicAdd(ws+4, 0.f);
    out[0] = a0 + a1 + a2 + a3;
    out[1] = a0; out[2] = a1; out[3] = a2; out[4] = a3; out[5] = a4;
  }
}

extern "C" void kernel_launch(void* const* d_in, const int* in_sizes, int n_in,
                              void* d_out, int out_size, void* d_ws, size_t ws_size,
                              hipStream_t stream){
  const float* xin    = (const float*)d_in[0];
  const float* labels = (const float*)d_in[1];
  const float* cw     = (const float*)d_in[2];
  const float* cb     = (const float*)d_in[3];
  float* out = (float*)d_out;
  float* ws  = (float*)d_ws;

  hipMemsetAsync(ws, 0, 64, stream);
  fused_kernel<<<NBLK, 256, 0, stream>>>(xin, labels, cw, cb, ws, out);
}

// Round 5
// 58.897 us; speedup vs baseline: 1.5077x; 1.5077x over previous
//
#include <hip/hip_runtime.h>
#include <math.h>

#define FD 76
#define FFD 5776
#define BD 16
#define CD 256
#define KD 50
#define AD 3

typedef float f32x2 __attribute__((ext_vector_type(2)));
typedef float f32x4 __attribute__((ext_vector_type(4)));

constexpr int NCELL = BD * FFD;          // 92416
constexpr int CBLK  = 128;               // cells per block
constexpr int NBLK  = NCELL / CBLK;      // 722

// ws layout (float offsets)
constexpr int ACC_O  = 0;                // [8]: [3]=lcls, [4]=l2cls (cls-kernel atomics)
constexpr int CNT_O  = 8;                // [1] int match counter
constexpr int LIST_O = 16;               // [1024][2] ints (cA, cls)
constexpr int TREC_O = 2064;             // [800][16] per-(b,k) records (16B aligned)
constexpr int WP_O   = TREC_O + 800*16;  // [256][16] reordered W' (16B aligned)
constexpr int BLK_O  = WP_O + 4096;      // [NBLK*4] per-block loss partials

__device__ __forceinline__ float sigm(float x){ return 1.f/(1.f + expf(-x)); }
__device__ __forceinline__ float clg(float x){ return logf(fmaxf(x, 1e-12f)); }
__device__ __forceinline__ float bce(float o, float t){ return -(t*clg(o) + (1.f-t)*clg(1.f-o)); }

// record layout [16]: 0:tx0 1:tx1 2:ty0 3:ty1 4:c7(0.7*ta|1e30) 5:code 6:txf 7:tyf
//                     8:twl 9:thl 10:scale 11:cls 12..15 pad
__global__ __launch_bounds__(256) void label_kernel(const float* __restrict__ labels,
                                                    const float* __restrict__ cw,
                                                    float* __restrict__ ws){
  if (blockIdx.x == 4){                  // build W'[c][16]: W'[c*16+j] = cw[o(j)*256+c]
    const int c = threadIdx.x;
    #pragma unroll
    for (int j = 0; j < 15; ++j){
      const int o = (j/5)*85 + (j%5);
      ws[WP_O + c*16 + j] = cw[o*CD + c];
    }
    ws[WP_O + c*16 + 15] = 0.f;
    return;
  }
  const int it = blockIdx.x*256 + threadIdx.x;
  if (blockIdx.x == 0 && threadIdx.x < 9){
    if (threadIdx.x < 8) ws[ACC_O + threadIdx.x] = 0.f;
    else ((int*)ws)[CNT_O] = 0;
  }
  if (it >= BD*KD) return;
  const float AWH[9][2] = {{1.25f,1.625f},{2.f,3.75f},{4.125f,2.875f},
                           {3.75f,7.625f},{7.75f,5.625f},{7.375f,14.875f},
                           {14.5f,11.25f},{19.5f,24.75f},{46.625f,40.75f}};
  const float* l = labels + it*5;
  const float cls = l[0], x = l[1], y = l[2], w = l[3], h = l[4];
  const bool valid = (cls + x + y + w + h) > 0.f;
  const float tx = x*FD, ty = y*FD, tw = w*FD, th = h*FD;
  const float ta = tw*th;
  float bestv = -1.f; int best = 0;
  #pragma unroll
  for (int n = 0; n < 9; ++n){
    const float mw = fminf(tw, AWH[n][0]), mh = fminf(th, AWH[n][1]);
    const float inter = (mw > 0.f && mh > 0.f) ? mw*mh : 0.f;
    const float iou = inter / (ta + AWH[n][0]*AWH[n][1] - inter);
    if (iou > bestv){ bestv = iou; best = n; }
  }
  const int bn = best % 3;
  const bool match = valid && (best < 3);
  const int ii = (int)tx, jj = (int)ty;
  const bool inb = (ii >= 0 && ii < FD && jj >= 0 && jj < FD);
  const float code = (match && inb) ? (float)(bn*FFD + jj*FD + ii) : -1.f;
  const float aw0 = (bn==0)?1.25f:((bn==1)?2.f:4.125f);
  const float aw1 = (bn==0)?1.625f:((bn==1)?3.75f:2.875f);
  float* r = ws + TREC_O + it*16;
  f32x4 r0 = {tx - tw*0.5f, tx + tw*0.5f, ty - th*0.5f, ty + th*0.5f};
  f32x4 r1 = {valid ? 0.7f*ta : 1e30f, code, tx - floorf(tx), ty - floorf(ty)};
  f32x4 r2 = {logf(tw/aw0 + 1e-16f), logf(th/aw1 + 1e-16f),
              sqrtf(2.f - ta/(float)(FD*FD)), cls};
  f32x4 r3 = {0.f, 0.f, 0.f, 0.f};
  *(f32x4*)(r+0) = r0; *(f32x4*)(r+4) = r1; *(f32x4*)(r+8) = r2; *(f32x4*)(r+12) = r3;
}

// ---------------- fused conv + epilogue (match resolve + IoU + losses) ----------------
// 722 blocks x 256 threads. Block = 128 cells (2/lane); wave wv owns 64 channels.
// W' read via uniform-address scalar loads (constant cache) — no LDS in the hot loop.
__global__ __launch_bounds__(256) void fused_kernel(const float* __restrict__ xin,
    const float* __restrict__ wp, const float* __restrict__ cb,
    float* __restrict__ ws, const float* __restrict__ trecg){
  __shared__ __align__(16) float trec[1600];   // 2 batches x 50 records x 16
  __shared__ __align__(16) float phase[7680];  // comb[4][15][128]
  __shared__ float redc[16];
  const int tid  = threadIdx.x;
  const int wv   = tid >> 6;
  const int lane = tid & 63;

  const int cell0blk = blockIdx.x*CBLK;
  const int bB0 = cell0blk / FFD;
  const int bB1 = (cell0blk + CBLK - 1) / FFD;

  // stage 2 batches of records (400 f32x4)
  {
    const f32x4* src = (const f32x4*)trecg;
    f32x4* dst = (f32x4*)trec;
    int q = tid;
    dst[q] = (q < 200) ? src[bB0*200 + q] : src[bB1*200 + q - 200];
    q = tid + 256;
    if (q < 400) dst[q] = src[bB1*200 + q - 200];
  }

  // ---- conv: lane owns cells (cell0blk + 2*lane, +1); wave owns 64 channels ----
  const int cellP = cell0blk + 2*lane;
  const int bC  = cellP / FFD;
  const int hwC = cellP - bC*FFD;
  const float* xp = xin + ((size_t)bC*CD + wv*64)*FFD + hwC;
  const int cb0 = wv*64;

  f32x2 acc[15];
  #pragma unroll
  for (int j = 0; j < 15; ++j) acc[j] = (f32x2){0.f, 0.f};

  f32x2 xa[16], xb[16];
  #pragma unroll
  for (int i = 0; i < 16; ++i) xa[i] = *(const f32x2*)(xp + (size_t)i*FFD);

  #define LOADC(buf, cc)                                                   \
    _Pragma("unroll")                                                      \
    for (int i = 0; i < 16; ++i)                                           \
      buf[i] = *(const f32x2*)(xp + (size_t)((cc)*16 + i)*FFD);
  #define FMAC(buf, cc)                                                    \
    _Pragma("unroll")                                                      \
    for (int i = 0; i < 16; ++i){                                          \
      const f32x4* wr = (const f32x4*)(wp + (size_t)(cb0 + (cc)*16 + i)*16);\
      const f32x4 w0 = wr[0], w1 = wr[1], w2 = wr[2], w3 = wr[3];          \
      const f32x2 xv = buf[i];                                             \
      acc[0]  += w0.x*xv; acc[1]  += w0.y*xv; acc[2]  += w0.z*xv;          \
      acc[3]  += w0.w*xv; acc[4]  += w1.x*xv; acc[5]  += w1.y*xv;          \
      acc[6]  += w1.z*xv; acc[7]  += w1.w*xv; acc[8]  += w2.x*xv;          \
      acc[9]  += w2.y*xv; acc[10] += w2.z*xv; acc[11] += w2.w*xv;          \
      acc[12] += w3.x*xv; acc[13] += w3.y*xv; acc[14] += w3.z*xv;          \
    }

  LOADC(xb, 1)  FMAC(xa, 0)
  LOADC(xa, 2)  FMAC(xb, 1)
  LOADC(xb, 3)  FMAC(xa, 2)
                FMAC(xb, 3)
  #undef LOADC
  #undef FMAC

  __syncthreads();                         // trec staged; phase free
  #pragma unroll
  for (int j = 0; j < 15; ++j)             // comb[wv][j][cell], j-major stride 128
    *(f32x2*)&phase[wv*1920 + j*128 + 2*lane] = acc[j];
  __syncthreads();

  // ---- epilogue: 384 (cell,anchor) items; threads 0..191 take pair (2t,2t+1) ----
  float lxy = 0.f, lwh = 0.f, lobj = 0.f, l2p = 0.f;
  if (tid < 192){
    const int it0 = 2*tid;
    const int a = it0 >> 7;
    const int cell0 = it0 & 127, cell1 = cell0 + 1;
    const float mw0 = (a==0)?1.25f:((a==1)?2.f:4.125f);
    const float mw1 = (a==0)?1.625f:((a==1)?3.75f:2.875f);
    float v0[5], v1[5];
    #pragma unroll
    for (int jj = 0; jj < 5; ++jj){
      const float bias = cb[a*85 + jj];
      float s0 = bias, s1 = bias;
      #pragma unroll
      for (int w2 = 0; w2 < 4; ++w2){
        const f32x2 q = *(const f32x2*)&phase[w2*1920 + (a*5+jj)*128 + cell0];
        s0 += q.x; s1 += q.y;
      }
      v0[jj] = s0; v1[jj] = s1;
    }
    const int g0 = cell0blk + cell0;
    const int bb = g0 / FFD;
    const int hw0 = g0 - bb*FFD,  hw1 = hw0 + 1;
    const int hh0 = hw0 / FD, wc0 = hw0 - hh0*FD;
    const int hh1 = hw1 / FD, wc1 = hw1 - hh1*FD;

    const float sx0 = sigm(v0[0]), sy0 = sigm(v0[1]), so0 = sigm(v0[4]);
    const float sx1 = sigm(v1[0]), sy1 = sigm(v1[1]), so1 = sigm(v1[4]);
    const float pw0 = expf(v0[2])*mw0, ph0 = expf(v0[3])*mw1;
    const float pw1 = expf(v1[2])*mw0, ph1 = expf(v1[3])*mw1;
    const float px0a = sx0 + wc0 - pw0*0.5f, px0b = sx0 + wc0 + pw0*0.5f;
    const float py0a = sy0 + hh0 - ph0*0.5f, py0b = sy0 + hh0 + ph0*0.5f;
    const float px1a = sx1 + wc1 - pw1*0.5f, px1b = sx1 + wc1 + pw1*0.5f;
    const float py1a = sy1 + hh1 - ph1*0.5f, py1b = sy1 + hh1 + ph1*0.5f;
    const float s7_0 = 0.7f*pw0*ph0, s7_1 = 0.7f*pw1*ph1;
    const float code0 = (float)(a*FFD + hw0), code1 = (float)(a*FFD + hw1);

    const int ub = (bb != bB0);
    const float* rb = trec + ub*800;
    float mx0 = -1e30f, mx1 = -1e30f;
    int ks0 = -1, ks1 = -1;
    for (int k = 0; k < KD; ++k){
      const f32x4 rA = *(const f32x4*)&rb[k*16];      // tx0 tx1 ty0 ty1
      const f32x2 rB = *(const f32x2*)&rb[k*16 + 4];  // c7, code
      {
        const float dx = fminf(px0b, rA.y) - fmaxf(px0a, rA.x);
        const float dy = fminf(py0b, rA.w) - fmaxf(py0a, rA.z);
        const float inter = fmaxf(dx, 0.f)*fmaxf(dy, 0.f);
        mx0 = fmaxf(mx0, 1.7f*inter - rB.x);
        ks0 = (rB.y == code0) ? k : ks0;
      }
      {
        const float dx = fminf(px1b, rA.y) - fmaxf(px1a, rA.x);
        const float dy = fminf(py1b, rA.w) - fmaxf(py1a, rA.z);
        const float inter = fmaxf(dx, 0.f)*fmaxf(dy, 0.f);
        mx1 = fmaxf(mx1, 1.7f*inter - rB.x);
        ks1 = (rB.y == code1) ? k : ks1;
      }
    }
    if (ks0 >= 0){
      const float txf = rb[ks0*16+6], tyf = rb[ks0*16+7];
      const float twl = rb[ks0*16+8], thl = rb[ks0*16+9];
      const float sc = rb[ks0*16+10], sc2 = sc*sc;
      lxy += sc2*(bce(sx0, txf) + bce(sy0, tyf));
      l2p += (sx0-txf)*(sx0-txf) + (sy0-tyf)*(sy0-tyf);
      const float d0 = v0[2]-twl, d1 = v0[3]-thl;
      lwh += 0.5f*sc2*(d0*d0 + d1*d1);
      l2p += sc2*(d0*d0 + d1*d1);
      lobj += -clg(so0); l2p += (so0-1.f)*(so0-1.f);
      const int pos = atomicAdd((int*)ws + CNT_O, 1);
      if (pos < 1024){ ((int*)ws)[LIST_O + pos*2] = (bb*AD + a)*FFD + hw0;
                       ((int*)ws)[LIST_O + pos*2 + 1] = (int)rb[ks0*16+11]; }
    } else if (!(mx0 > s7_0)){ lobj += -clg(1.f - so0); l2p += so0*so0; }
    if (ks1 >= 0){
      const float txf = rb[ks1*16+6], tyf = rb[ks1*16+7];
      const float twl = rb[ks1*16+8], thl = rb[ks1*16+9];
      const float sc = rb[ks1*16+10], sc2 = sc*sc;
      lxy += sc2*(bce(sx1, txf) + bce(sy1, tyf));
      l2p += (sx1-txf)*(sx1-txf) + (sy1-tyf)*(sy1-tyf);
      const float d0 = v1[2]-twl, d1 = v1[3]-thl;
      lwh += 0.5f*sc2*(d0*d0 + d1*d1);
      l2p += sc2*(d0*d0 + d1*d1);
      lobj += -clg(so1); l2p += (so1-1.f)*(so1-1.f);
      const int pos = atomicAdd((int*)ws + CNT_O, 1);
      if (pos < 1024){ ((int*)ws)[LIST_O + pos*2] = (bb*AD + a)*FFD + hw1;
                       ((int*)ws)[LIST_O + pos*2 + 1] = (int)rb[ks1*16+11]; }
    } else if (!(mx1 > s7_1)){ lobj += -clg(1.f - so1); l2p += so1*so1; }
  }

  #pragma unroll
  for (int o = 32; o > 0; o >>= 1){
    lxy  += __shfl_down(lxy,  o, 64);
    lwh  += __shfl_down(lwh,  o, 64);
    lobj += __shfl_down(lobj, o, 64);
    l2p  += __shfl_down(l2p,  o, 64);
  }
  __syncthreads();
  if (lane == 0){
    redc[wv*4+0] = lxy; redc[wv*4+1] = lwh; redc[wv*4+2] = lobj; redc[wv*4+3] = l2p;
  }
  __syncthreads();
  if (tid < 4)
    ws[BLK_O + blockIdx.x*4 + tid] =
      redc[0*4+tid] + redc[1*4+tid] + redc[2*4+tid] + redc[3*4+tid];
}

// ---------------- cls kernel: 80 channels at matched cells only -----------------------
__global__ __launch_bounds__(128) void cls_kernel(const float* __restrict__ xin,
    const float* __restrict__ cw, const float* __restrict__ cb, float* __restrict__ ws){
  const int cnt = ((const int*)ws)[CNT_O];
  if ((int)blockIdx.x >= cnt) return;
  const int cA  = ((const int*)ws)[LIST_O + blockIdx.x*2];
  const int cls = ((const int*)ws)[LIST_O + blockIdx.x*2 + 1];
  const int b   = cA / (AD*FFD);
  const int rem = cA - b*AD*FFD;
  const int a   = rem / FFD;
  const int hw  = rem - a*FFD;
  __shared__ float xs[256];
  __shared__ float sm[128];
  const int tid = threadIdx.x;
  const float* xb = xin + ((size_t)b*CD)*FFD + hw;
  xs[tid]       = xb[(size_t)tid*FFD];
  xs[tid + 128] = xb[(size_t)(tid + 128)*FFD];
  __syncthreads();
  float lcls = 0.f, l2p = 0.f;
  if (tid < 80){
    const int o = a*85 + 5 + tid;
    const float* wr = cw + o*CD;
    float s = 0.f;
    #pragma unroll 8
    for (int c = 0; c < CD; ++c) s += xs[c]*wr[c];
    const float e = sigm(s + cb[o]);
    const float t = (tid == cls) ? 1.f : 0.f;
    lcls = bce(e, t);
    l2p  = (e - t)*(e - t);
  }
  sm[tid] = lcls; __syncthreads();
  for (int s2 = 64; s2 > 0; s2 >>= 1){ if (tid < s2) sm[tid] += sm[tid+s2]; __syncthreads(); }
  if (tid == 0) atomicAdd(ws + ACC_O + 3, sm[0]);
  __syncthreads();
  sm[tid] = l2p; __syncthreads();
  for (int s2 = 64; s2 > 0; s2 >>= 1){ if (tid < s2) sm[tid] += sm[tid+s2]; __syncthreads(); }
  if (tid == 0) atomicAdd(ws + ACC_O + 4, sm[0]);
}

// ---------------- finalize ------------------------------------------------------------
__global__ __launch_bounds__(256) void fin_kernel(const float* __restrict__ ws,
                                                  float* __restrict__ out){
  __shared__ float sm[256];
  const int tid = threadIdx.x;
  float p[4] = {0,0,0,0};
  for (int i = tid; i < NBLK; i += 256){
    p[0] += ws[BLK_O + i*4 + 0];
    p[1] += ws[BLK_O + i*4 + 1];
    p[2] += ws[BLK_O + i*4 + 2];
    p[3] += ws[BLK_O + i*4 + 3];
  }
  float tot[4];
  #pragma unroll
  for (int r = 0; r < 4; ++r){
    __syncthreads();
    sm[tid] = p[r];
    __syncthreads();
    for (int s = 128; s > 0; s >>= 1){
      if (tid < s) sm[tid] += sm[tid + s];
      __syncthreads();
    }
    tot[r] = sm[0];
  }
  if (tid == 0){
    const float lxy = tot[0], lwh = tot[1], lobj = tot[2];
    const float lcls = ws[ACC_O+3];
    const float l2   = tot[3] + ws[ACC_O+4];
    out[0] = lxy + lwh + lobj + lcls;
    out[1] = lxy; out[2] = lwh; out[3] = lobj; out[4] = lcls; out[5] = l2;
  }
}

extern "C" void kernel_launch(void* const* d_in, const int* in_sizes, int n_in,
                              void* d_out, int out_size, void* d_ws, size_t ws_size,
                              hipStream_t stream){
  const float* xin    = (const float*)d_in[0];
  const float* labels = (const float*)d_in[1];
  const float* cw     = (const float*)d_in[2];
  const float* cb     = (const float*)d_in[3];
  float* out = (float*)d_out;
  float* ws  = (float*)d_ws;

  label_kernel<<<5, 256, 0, stream>>>(labels, cw, ws);
  fused_kernel<<<NBLK, 256, 0, stream>>>(xin, ws + WP_O, cb, ws, ws + TREC_O);
  cls_kernel<<<800, 128, 0, stream>>>(xin, cw, cb, ws);
  fin_kernel<<<1, 256, 0, stream>>>(ws, out);
}